// Round 1
// 267.402 us; speedup vs baseline: 1.0417x; 1.0417x over previous
//
#include <hip/hip_runtime.h>
#include <hip/hip_bf16.h>

#define DM 256
#define NH 8
#define HD 32
#define NLV 3
#define NPT 4
#define NLP 12
#define BB 16
#define LQ 300
#define NT 8400
#define MROWS (BB * NT)      // 134400
#define QROWS (BB * LQ)      // 4800
#define KP2 72               // padded LDS K-stride for A tiles (BK=64)

typedef __bf16 bf16x8 __attribute__((ext_vector_type(8)));
typedef float  f32x16 __attribute__((ext_vector_type(16)));

// ---------------------------------------------------------------------------
// Kernel 0: pre-tile weights to bf16, all fragment-major:
//   frag(g, kh, n, j) holds W[k = g*16 + kh*8 + j][n]; lanes (consecutive n)
//   read contiguous 16 B, so 32 lanes = 512 B coalesced from L2.
// blocks 0..255   -> Wf  [g*2+kh][n(256)][8]  from W_val   (stride 2048/g-half)
// blocks 256..543 -> Wf2 [g*2+kh][n(288)][8]  from [W_off | W_attn] (stride 2304)
// blocks 544..799 -> Wf3 [g*2+kh][n(256)][8]  from W_out   (stride 2048)
// ---------------------------------------------------------------------------
__global__ void k_wt(const float* __restrict__ W_val,
                     const float* __restrict__ W_off,
                     const float* __restrict__ W_attn,
                     const float* __restrict__ W_out,
                     __hip_bfloat16* __restrict__ Wf,
                     __hip_bfloat16* __restrict__ Wf2,
                     __hip_bfloat16* __restrict__ Wf3)
{
    const int n = blockIdx.x;
    const int k = threadIdx.x;
    if (n < 256) {
        Wf[(size_t)(k >> 3) * 2048 + n * 8 + (k & 7)] =
            __float2bfloat16(W_val[(size_t)k * 256 + n]);
    } else if (n < 544) {
        const int n2 = n - 256;   // 0..287
        float v = (n2 < 192) ? W_off[(size_t)k * 192 + n2]
                             : W_attn[(size_t)k * 96 + (n2 - 192)];
        Wf2[(size_t)(k >> 3) * 2304 + n2 * 8 + (k & 7)] = __float2bfloat16(v);
    } else {
        const int n3 = n - 544;   // 0..255
        Wf3[(size_t)(k >> 3) * 2048 + n3 * 8 + (k & 7)] =
            __float2bfloat16(W_out[(size_t)k * 256 + n3]);
    }
}

// ---------------------------------------------------------------------------
// Kernel 1 (merged): blocks [0, 4200)   -> value = input_flatten @ W_val + b_val
//                    blocks [4200,4350) -> [off|attn] = query @ [W_off|W_attn]+b
// The small Q-GEMM has no dependency on the value projection; merging hides
// its latency-bound 150 blocks under the big GEMM's tail and saves a launch.
// Both paths: A fp32 -> bf16 via LDS (double-buffered, ONE barrier/K-iter),
// W fragments direct from L2-resident global (loads stay in flight across
// the barrier).  BM=32, BK=64.
// ---------------------------------------------------------------------------
__global__ __launch_bounds__(256) void k_mm1(
    const float* __restrict__ A,             // (134400, 256) fp32
    const __hip_bfloat16* __restrict__ Wf,   // fragment-major W_val
    const float* __restrict__ bval,          // (256,)
    __hip_bfloat16* __restrict__ V,          // (16, 8, 8400, 32)
    const float* __restrict__ Q,             // (4800, 256) fp32
    const __hip_bfloat16* __restrict__ Wf2,  // fragment-major [W_off|W_attn]
    const float* __restrict__ boff,          // (192,)
    const float* __restrict__ battn,         // (96,)
    float* __restrict__ off_out,             // (4800, 192)
    float* __restrict__ attn_out)            // (4800, 96)
{
    __shared__ __hip_bfloat16 As[2][32 * KP2];   // 2 x 4.5 KB

    const int t    = threadIdx.x;
    const int wave = t >> 6;
    const int lane = t & 63;
    const int lm   = lane & 31;
    const int kh   = lane >> 5;
    const int lk   = kh * 8;
    const int ar   = t >> 3;          // A row 0..31
    const int ak   = (t & 7) * 8;     // A k-chunk 0..56

    if (blockIdx.x < MROWS / 32) {
        // ---------------- value projection ----------------
        const int m0 = blockIdx.x * 32;

        f32x16 acc[2];
#pragma unroll
        for (int j = 0; j < 2; j++)
#pragma unroll
            for (int e = 0; e < 16; e++) acc[j][e] = 0.f;

        const __hip_bfloat16* wf0 = Wf + (size_t)(wave * 64 + lm) * 8 + kh * 2048;

        {
            const float* ap = A + (size_t)(m0 + ar) * 256 + ak;
            float4 a0 = *(const float4*)ap;
            float4 a1 = *(const float4*)(ap + 4);
            union { __hip_bfloat162 h2[4]; bf16x8 v; } ua;
            ua.h2[0] = __float22bfloat162_rn(make_float2(a0.x, a0.y));
            ua.h2[1] = __float22bfloat162_rn(make_float2(a0.z, a0.w));
            ua.h2[2] = __float22bfloat162_rn(make_float2(a1.x, a1.y));
            ua.h2[3] = __float22bfloat162_rn(make_float2(a1.z, a1.w));
            *(bf16x8*)(&As[0][ar * KP2 + ak]) = ua.v;
        }
        __syncthreads();

#pragma unroll
        for (int it = 0; it < 4; ++it) {
            const int buf = it & 1;
            float4 na0, na1;
            if (it < 3) {
                const float* ap = A + (size_t)(m0 + ar) * 256 + (it + 1) * 64 + ak;
                na0 = *(const float4*)ap;
                na1 = *(const float4*)(ap + 4);
            }
#pragma unroll
            for (int ks = 0; ks < 4; ++ks) {
                const int g = it * 4 + ks;
                bf16x8 af = *(const bf16x8*)(&As[buf][lm * KP2 + ks * 16 + lk]);
                bf16x8 b0 = *(const bf16x8*)(wf0 + (size_t)g * 4096);
                bf16x8 b1 = *(const bf16x8*)(wf0 + (size_t)g * 4096 + 256);
                acc[0] = __builtin_amdgcn_mfma_f32_32x32x16_bf16(af, b0, acc[0], 0, 0, 0);
                acc[1] = __builtin_amdgcn_mfma_f32_32x32x16_bf16(af, b1, acc[1], 0, 0, 0);
            }
            if (it < 3) {
                union { __hip_bfloat162 h2[4]; bf16x8 v; } ua;
                ua.h2[0] = __float22bfloat162_rn(make_float2(na0.x, na0.y));
                ua.h2[1] = __float22bfloat162_rn(make_float2(na0.z, na0.w));
                ua.h2[2] = __float22bfloat162_rn(make_float2(na1.x, na1.y));
                ua.h2[3] = __float22bfloat162_rn(make_float2(na1.z, na1.w));
                *(bf16x8*)(&As[buf ^ 1][ar * KP2 + ak]) = ua.v;
                __syncthreads();
            }
        }

#pragma unroll
        for (int j = 0; j < 2; j++) {
            const int n  = wave * 64 + j * 32 + lm;
            const float bn = bval[n];
            const int h  = n >> 5;
            const int d  = n & 31;
#pragma unroll
            for (int r = 0; r < 16; r++) {
                int rl = (r & 3) + 8 * (r >> 2) + 4 * kh;
                int m  = m0 + rl;
                int b  = m / NT;
                int pos = m - b * NT;
                V[((size_t)(b * NH + h) * NT + pos) * HD + d] =
                    __float2bfloat16(acc[j][r] + bn);
            }
        }
    } else {
        // ---------------- offset/attention projection ----------------
        const int m0 = (blockIdx.x - MROWS / 32) * 32;

        f32x16 acc[3];
#pragma unroll
        for (int j = 0; j < 3; j++)
#pragma unroll
            for (int e = 0; e < 16; e++) acc[j][e] = 0.f;

        const __hip_bfloat16* wf0 = Wf2 + (size_t)(wave * 96 + lm) * 8 + kh * 2304;

        {
            const float* ap = Q + (size_t)(m0 + ar) * 256 + ak;
            float4 a0 = *(const float4*)ap;
            float4 a1 = *(const float4*)(ap + 4);
            union { __hip_bfloat162 h2[4]; bf16x8 v; } ua;
            ua.h2[0] = __float22bfloat162_rn(make_float2(a0.x, a0.y));
            ua.h2[1] = __float22bfloat162_rn(make_float2(a0.z, a0.w));
            ua.h2[2] = __float22bfloat162_rn(make_float2(a1.x, a1.y));
            ua.h2[3] = __float22bfloat162_rn(make_float2(a1.z, a1.w));
            *(bf16x8*)(&As[0][ar * KP2 + ak]) = ua.v;
        }
        __syncthreads();

#pragma unroll
        for (int it = 0; it < 4; ++it) {
            const int buf = it & 1;
            float4 na0, na1;
            if (it < 3) {
                const float* ap = Q + (size_t)(m0 + ar) * 256 + (it + 1) * 64 + ak;
                na0 = *(const float4*)ap;
                na1 = *(const float4*)(ap + 4);
            }
#pragma unroll
            for (int ks = 0; ks < 4; ++ks) {
                const int g = it * 4 + ks;
                bf16x8 af = *(const bf16x8*)(&As[buf][lm * KP2 + ks * 16 + lk]);
                if (wave < 3) {
#pragma unroll
                    for (int j = 0; j < 3; j++) {
                        bf16x8 bf = *(const bf16x8*)(wf0 + (size_t)g * 4608 + j * 256);
                        acc[j] = __builtin_amdgcn_mfma_f32_32x32x16_bf16(af, bf, acc[j], 0, 0, 0);
                    }
                }
            }
            if (it < 3) {
                union { __hip_bfloat162 h2[4]; bf16x8 v; } ua;
                ua.h2[0] = __float22bfloat162_rn(make_float2(na0.x, na0.y));
                ua.h2[1] = __float22bfloat162_rn(make_float2(na0.z, na0.w));
                ua.h2[2] = __float22bfloat162_rn(make_float2(na1.x, na1.y));
                ua.h2[3] = __float22bfloat162_rn(make_float2(na1.z, na1.w));
                *(bf16x8*)(&As[buf ^ 1][ar * KP2 + ak]) = ua.v;
                __syncthreads();
            }
        }

        if (wave < 3) {
#pragma unroll
            for (int j = 0; j < 3; j++) {
                const int n = wave * 96 + j * 32 + lm;
                const float bias_ = (n < 192) ? boff[n] : battn[n - 192];
#pragma unroll
                for (int r = 0; r < 16; r++) {
                    int rl = (r & 3) + 8 * (r >> 2) + 4 * kh;
                    int m  = m0 + rl;
                    float v = acc[j][r] + bias_;
                    if (n < 192) off_out[(size_t)m * 192 + n] = v;
                    else         attn_out[(size_t)m * 96 + (n - 192)] = v;
                }
            }
        }
    }
}

// ---------------------------------------------------------------------------
// Kernel 3: softmax + sampling.  2 queries per block (256 thr = 2 x 128).
// XCD-locality swizzle: hardware round-robins blockIdx%8 across the 8 XCDs,
// so bind batch image b to XCD b%8 -> each XCD's 4 MB L2 serves a ~8.6 MB
// (2-image) V working set instead of the full 68.8 MB random mix.
// ---------------------------------------------------------------------------
__global__ __launch_bounds__(256) void k_sample(
    const float* __restrict__ off_raw,   // (4800, 192)  (h,l,p,2)
    const float* __restrict__ attn_raw,  // (4800, 96)   (h, l*4+p)
    const float* __restrict__ refp,      // (16, 300, 3, 2)
    const __hip_bfloat16* __restrict__ V,// (16, 8, 8400, 32)
    __hip_bfloat16* __restrict__ sampled)// (4800, 256) bf16
{
    const int t  = threadIdx.x;
    const int q2 = t >> 7;          // 0..1
    const int tq = t & 127;

    // swizzle: bid -> (xcd, slot); image b = xcd + 8*(slot>=150)
    const int bid  = blockIdx.x;          // 0..2399
    const int xcd  = bid & 7;
    const int slot = bid >> 3;            // 0..299
    const int hi   = (slot >= 150) ? 1 : 0;
    const int b    = xcd + (hi << 3);
    const int bq   = b * LQ + (slot - hi * 150) * 2 + q2;

    __shared__ float aw[2][96];
    __shared__ float wc[2][96][4];
    __shared__ int   ic[2][96][4];

    if (tq < 8) {
        float v[12];
        float mx = -1e30f;
#pragma unroll
        for (int i = 0; i < 12; i++) {
            v[i] = attn_raw[(size_t)bq * 96 + tq * 12 + i];
            mx = fmaxf(mx, v[i]);
        }
        float s = 0.f;
#pragma unroll
        for (int i = 0; i < 12; i++) { v[i] = expf(v[i] - mx); s += v[i]; }
        float inv = 1.f / s;
#pragma unroll
        for (int i = 0; i < 12; i++) aw[q2][tq * 12 + i] = v[i] * inv;
    }
    __syncthreads();

    if (tq < 96) {
        const float dims[3]  = {80.f, 40.f, 20.f};
        const int startsl[3] = {0, 6400, 8000};
        const int idiml[3]   = {80, 40, 20};
        int h = tq / 12, lp = tq - h * 12, l = lp >> 2, p = lp & 3;
        float ox = off_raw[(size_t)bq * 192 + ((h * 3 + l) * 4 + p) * 2 + 0];
        float oy = off_raw[(size_t)bq * 192 + ((h * 3 + l) * 4 + p) * 2 + 1];
        float rx = refp[(size_t)bq * 6 + l * 2 + 0];
        float ry = refp[(size_t)bq * 6 + l * 2 + 1];
        float D  = dims[l];
        float lx = rx + ox / D;
        float ly = ry + oy / D;
        float ix = lx * D - 0.5f;
        float iy = ly * D - 0.5f;
        const int Dl = idiml[l];
        const int st = startsl[l];

        float fix = floorf(ix), fiy = floorf(iy);
        int ix0 = (int)fix, iy0 = (int)fiy;
        int ix1 = ix0 + 1, iy1 = iy0 + 1;
        float fx = ix - fix, fy = iy - fiy;

        float mx0 = (ix0 >= 0 && ix0 < Dl) ? 1.f : 0.f;
        float mx1 = (ix1 >= 0 && ix1 < Dl) ? 1.f : 0.f;
        float my0 = (iy0 >= 0 && iy0 < Dl) ? 1.f : 0.f;
        float my1 = (iy1 >= 0 && iy1 < Dl) ? 1.f : 0.f;

        int cx0 = min(max(ix0, 0), Dl - 1);
        int cx1 = min(max(ix1, 0), Dl - 1);
        int cy0 = min(max(iy0, 0), Dl - 1);
        int cy1 = min(max(iy1, 0), Dl - 1);

        float a = aw[q2][tq];
        wc[q2][tq][0] = (1.f - fx) * (1.f - fy) * mx0 * my0 * a;
        wc[q2][tq][1] = fx * (1.f - fy) * mx1 * my0 * a;
        wc[q2][tq][2] = (1.f - fx) * fy * mx0 * my1 * a;
        wc[q2][tq][3] = fx * fy * mx1 * my1 * a;
        ic[q2][tq][0] = (st + cy0 * Dl + cx0) * HD;
        ic[q2][tq][1] = (st + cy0 * Dl + cx1) * HD;
        ic[q2][tq][2] = (st + cy1 * Dl + cx0) * HD;
        ic[q2][tq][3] = (st + cy1 * Dl + cx1) * HD;
    }
    __syncthreads();

    const int h  = tq >> 4;
    const int dp = (tq & 15) * 2;
    const __hip_bfloat16* vb = V + (size_t)(b * NH + h) * NT * HD + dp;

    float acc0 = 0.f, acc1 = 0.f;
#pragma unroll
    for (int lp = 0; lp < 12; lp++) {
        const int s = h * 12 + lp;
        float4 w4 = *(const float4*)(&wc[q2][s][0]);
        int4   i4 = *(const int4*)(&ic[q2][s][0]);
        float2 v00 = __bfloat1622float2(*(const __hip_bfloat162*)(vb + i4.x));
        float2 v01 = __bfloat1622float2(*(const __hip_bfloat162*)(vb + i4.y));
        float2 v10 = __bfloat1622float2(*(const __hip_bfloat162*)(vb + i4.z));
        float2 v11 = __bfloat1622float2(*(const __hip_bfloat162*)(vb + i4.w));
        acc0 = fmaf(w4.x, v00.x, fmaf(w4.y, v01.x, fmaf(w4.z, v10.x, fmaf(w4.w, v11.x, acc0))));
        acc1 = fmaf(w4.x, v00.y, fmaf(w4.y, v01.y, fmaf(w4.z, v10.y, fmaf(w4.w, v11.y, acc1))));
    }
    *(__hip_bfloat162*)(sampled + (size_t)bq * 256 + h * 32 + dp) =
        __float22bfloat162_rn(make_float2(acc0, acc1));
}

// ---------------------------------------------------------------------------
// Kernel 4 (MFMA): out = sampled(bf16) @ W_out + b_out.
// W fragments direct from L2-resident fragment-major Wf3 (no Ws staging, no
// extra barrier); A bf16 staged via LDS double-buffer, one barrier per iter.
// ---------------------------------------------------------------------------
__global__ __launch_bounds__(256) void k_outproj(
    const __hip_bfloat16* __restrict__ A,    // (4800, 256) bf16
    const __hip_bfloat16* __restrict__ Wf3,  // fragment-major W_out
    const float* __restrict__ bias,          // (256,)
    float* __restrict__ out)                 // (4800, 256)
{
    __shared__ __hip_bfloat16 As[2][32 * KP2];

    const int t    = threadIdx.x;
    const int m0   = blockIdx.x * 32;
    const int wave = t >> 6;
    const int lane = t & 63;
    const int lm   = lane & 31;
    const int kh   = lane >> 5;
    const int lk   = kh * 8;
    const int ar   = t >> 3;
    const int ak   = (t & 7) * 8;

    f32x16 acc[2];
#pragma unroll
    for (int j = 0; j < 2; j++)
#pragma unroll
        for (int e = 0; e < 16; e++) acc[j][e] = 0.f;

    const __hip_bfloat16* wf0 = Wf3 + (size_t)(wave * 64 + lm) * 8 + kh * 2048;

    *(bf16x8*)(&As[0][ar * KP2 + ak]) =
        *(const bf16x8*)(A + (size_t)(m0 + ar) * 256 + ak);
    __syncthreads();

#pragma unroll
    for (int it = 0; it < 4; ++it) {
        const int buf = it & 1;
        bf16x8 na;
        if (it < 3)
            na = *(const bf16x8*)(A + (size_t)(m0 + ar) * 256 + (it + 1) * 64 + ak);
#pragma unroll
        for (int ks = 0; ks < 4; ++ks) {
            const int g = it * 4 + ks;
            bf16x8 af = *(const bf16x8*)(&As[buf][lm * KP2 + ks * 16 + lk]);
            bf16x8 b0 = *(const bf16x8*)(wf0 + (size_t)g * 4096);
            bf16x8 b1 = *(const bf16x8*)(wf0 + (size_t)g * 4096 + 256);
            acc[0] = __builtin_amdgcn_mfma_f32_32x32x16_bf16(af, b0, acc[0], 0, 0, 0);
            acc[1] = __builtin_amdgcn_mfma_f32_32x32x16_bf16(af, b1, acc[1], 0, 0, 0);
        }
        if (it < 3) {
            *(bf16x8*)(&As[buf ^ 1][ar * KP2 + ak]) = na;
            __syncthreads();
        }
    }

#pragma unroll
    for (int j = 0; j < 2; j++) {
        const int n = wave * 64 + j * 32 + lm;
        const float bn = bias[n];
#pragma unroll
        for (int r = 0; r < 16; r++) {
            int rl = (r & 3) + 8 * (r >> 2) + 4 * kh;
            int m  = m0 + rl;
            out[(size_t)m * 256 + n] = acc[j][r] + bn;
        }
    }
}

// ---------------------------------------------------------------------------
extern "C" void kernel_launch(void* const* d_in, const int* in_sizes, int n_in,
                              void* d_out, int out_size, void* d_ws, size_t ws_size,
                              hipStream_t stream) {
    const float* query  = (const float*)d_in[0];
    const float* refp   = (const float*)d_in[1];
    const float* inputf = (const float*)d_in[2];
    const float* W_off  = (const float*)d_in[3];
    const float* b_off  = (const float*)d_in[4];
    const float* W_attn = (const float*)d_in[5];
    const float* b_attn = (const float*)d_in[6];
    const float* W_val  = (const float*)d_in[7];
    const float* b_val  = (const float*)d_in[8];
    const float* W_out  = (const float*)d_in[9];
    const float* b_out  = (const float*)d_in[10];
    float* out = (float*)d_out;

    char* ws = (char*)d_ws;
    __hip_bfloat16* value   = (__hip_bfloat16*)ws;                       // 68,812,800
    float* off_raw          = (float*)(ws + 68812800);                   //  3,686,400
    float* attn_raw         = (float*)(ws + 72499200);                   //  1,843,200
    __hip_bfloat16* sampled = (__hip_bfloat16*)(ws + 74342400);          //  2,457,600
    __hip_bfloat16* Wf      = (__hip_bfloat16*)(ws + 76800000);          //    131,072
    __hip_bfloat16* Wf2     = (__hip_bfloat16*)(ws + 76931072);          //    147,456
    __hip_bfloat16* Wf3     = (__hip_bfloat16*)(ws + 77078528);          //    131,072

    k_wt<<<800, 256, 0, stream>>>(W_val, W_off, W_attn, W_out, Wf, Wf2, Wf3);
    k_mm1<<<MROWS / 32 + QROWS / 32, 256, 0, stream>>>(
        inputf, Wf, b_val, value, query, Wf2, b_off, b_attn, off_raw, attn_raw);
    k_sample<<<QROWS / 2, 256, 0, stream>>>(off_raw, attn_raw, refp, value, sampled);
    k_outproj<<<QROWS / 32, 256, 0, stream>>>(sampled, Wf3, b_out, out);
}